// Round 10
// baseline (1973.345 us; speedup 1.0000x reference)
//
#include <hip/hip_runtime.h>

// ---------------- problem constants ----------------
#define BB    128
#define BUFF  64
#define STK   48
#define NCOMP 8
#define HIST  96
#define WDIM  300
#define POSD  50
#define CAD   50
#define HAD   50
#define FC    128
#define UU    256
#define NOUT  82

typedef __bf16 bf16;
typedef __attribute__((ext_vector_type(8))) __bf16 bf16x8;
typedef __attribute__((ext_vector_type(4))) float   f32x4;

__device__ __forceinline__ float sigf(float x)   { return 1.f / (1.f + __expf(-x)); }
__device__ __forceinline__ float tanhf_(float x) { return 1.f - 2.f / (1.f + __expf(2.f * x)); }

// pack two consecutive fp32 values as two bf16 in one u32
__device__ __forceinline__ unsigned pack2(const float* p) {
  union { unsigned u; bf16 h[2]; } r;
  r.h[0] = (bf16)p[0]; r.h[1] = (bf16)p[1];
  return r.u;
}

// =====================================================================
// Kernel 1: embedding MLP.  rows 0..98303 = comp, 98304..106495 = buff.
// out = relu(concat(w_emb[word](300), p_emb[pos](50)) @ emb_W(350x128) + b)
// =====================================================================
__global__ __launch_bounds__(256) void k_emb(
    const int* bw, const int* bp, const int* cw, const int* cp,
    const float* w_emb, const float* p_emb, const float* embW, const float* embB,
    bf16* comp_emb, bf16* buff_emb)
{
  __shared__ __align__(16) char sm[138752];
  bf16*  A  = (bf16*)sm;                    // [64][360]
  bf16*  Wt = (bf16*)(sm + 46080);          // [128][360] (transposed: [n][k])
  float* sb = (float*)(sm + 46080 + 92160); // [128]

  const int tid = threadIdx.x;
  const int r0  = blockIdx.x * 64;

  // stage A rows (word||pos||0), converting fp32 -> bf16, 2 per u32
  for (int i = tid; i < 64 * 176; i += 256) {
    int m = i / 176, c2 = i % 176, e0 = 2 * c2;
    int r = r0 + m;
    unsigned v;
    if (e0 < 300) {
      int word = (r < 98304) ? cw[r] : bw[r - 98304];
      v = pack2(w_emb + word * 300 + e0);
    } else if (e0 < 350) {
      int pos = (r < 98304) ? cp[r] : bp[r - 98304];
      v = pack2(p_emb + pos * 50 + (e0 - 300));
    } else v = 0u;
    *(unsigned*)(A + m * 360 + e0) = v;
  }
  // stage W transposed (fp32 -> bf16)
  for (int i = tid; i < 350 * 128; i += 256) {
    int k = i >> 7, n = i & 127;
    Wt[n * 360 + k] = (bf16)embW[i];
  }
  // zero k=350,351 in Wt
  { int i = tid; if (i < 256) { int n = i >> 1; Wt[n * 360 + 350 + (i & 1)] = (bf16)0.f; } }
  if (tid < 128) sb[tid] = embB[tid];
  __syncthreads();

  const int wv = tid >> 6, lane = tid & 63, l15 = lane & 15, quad = lane >> 4;
  f32x4 acc[8];
#pragma unroll
  for (int i = 0; i < 8; ++i) acc[i] = (f32x4){0.f, 0.f, 0.f, 0.f};

  const bf16* Arow = A + (wv * 16 + l15) * 360;
  for (int ks = 0; ks < 11; ++ks) {
    int kq = ks * 32 + quad * 8;
    bf16x8 a = *(const bf16x8*)(Arow + kq);
#pragma unroll
    for (int nt = 0; nt < 8; ++nt) {
      bf16x8 b = *(const bf16x8*)(Wt + (nt * 16 + l15) * 360 + kq);
      acc[nt] = __builtin_amdgcn_mfma_f32_16x16x32_bf16(a, b, acc[nt], 0, 0, 0);
    }
  }
#pragma unroll
  for (int nt = 0; nt < 8; ++nt)
#pragma unroll
    for (int rr = 0; rr < 4; ++rr) {
      int row = wv * 16 + quad * 4 + rr;
      int n   = nt * 16 + l15;
      float z = fmaxf(acc[nt][rr] + sb[n], 0.f);
      int r = r0 + row;
      bf16 o = (bf16)z;
      if (r < 98304) comp_emb[r * 128 + n] = o;
      else           buff_emb[(r - 98304) * 128 + n] = o;
    }
}

// =====================================================================
// Kernel 2: compose.  16 (b,s) pairs per block, 8 sequential steps in LDS.
// =====================================================================
__global__ __launch_bounds__(256) void k_compose(
    const int* cw, const int* caid, const int* calen,
    const bf16* comp_emb, const float* ca_emb, const float* recW, const float* recB,
    bf16* stack_emb)
{
  __shared__ __align__(16) char sm[129344];
  bf16*  Wt   = (bf16*)sm;              // [128][328]
  bf16*  X    = (bf16*)(sm + 83968);    // [16][328]
  bf16*  VALS = (bf16*)(sm + 94464);    // [16][8][128]
  float* recb = (float*)(sm + 127232);  // [128]
  int*   IH   = (int*)(sm + 127744);    // [16][8]
  int*   ID   = (int*)(sm + 128256);
  int*   AN   = (int*)(sm + 128768);
  int*   ALEN = (int*)(sm + 129280);    // [16]

  const int tid = threadIdx.x;
  const int bs0 = blockIdx.x * 16;

  for (int i = tid; i < 306 * 128; i += 256) {
    int k = i >> 7, n = i & 127;
    Wt[n * 328 + k] = (bf16)recW[i];
  }
  for (int i = tid; i < 128 * 22; i += 256) {  // zero pad rows 306..327
    int n = i / 22, k = 306 + i % 22;
    Wt[n * 328 + k] = (bf16)0.f;
  }
  if (tid < 128) recb[tid] = recB[tid];
  if (tid < 16) {
    int bs = bs0 + tid;
    int hid[8], did[8];
#pragma unroll
    for (int m = 0; m < 8; ++m) { hid[m] = cw[bs * 16 + 2 * m]; did[m] = cw[bs * 16 + 2 * m + 1]; }
    for (int n = 0; n < 8; ++n) {
      int ih = -1, idd = -1;
      for (int m = 0; m < n; ++m) { if (hid[m] == hid[n]) ih = m; if (hid[m] == did[n]) idd = m; }
      IH[tid * 8 + n] = ih; ID[tid * 8 + n] = idd; AN[tid * 8 + n] = caid[bs * 8 + n];
    }
    ALEN[tid] = calen[bs];
  }
  __syncthreads();

  const int wv = tid >> 6, lane = tid & 63, l15 = lane & 15, quad = lane >> 4;

  for (int n = 0; n < 8; ++n) {
    // stage X = [head_e(128) | act(50) | dep_e(128) | 0 pad] per pair
    for (int i = tid; i < 16 * 160; i += 256) {
      int p = i / 160, c2 = i % 160, e0 = 2 * c2;
      int bs = bs0 + p;
      unsigned v;
      if (e0 < 128) {
        int ih = IH[p * 8 + n];
        v = (ih >= 0) ? *(const unsigned*)(VALS + (p * 8 + ih) * 128 + e0)
                      : *(const unsigned*)(comp_emb + (bs * 16 + 2 * n) * 128 + e0);
      } else if (e0 < 178) {
        v = pack2(ca_emb + AN[p * 8 + n] * 50 + (e0 - 128));
      } else if (e0 < 306) {
        int e = e0 - 178;
        int idd = ID[p * 8 + n];
        v = (idd >= 0) ? *(const unsigned*)(VALS + (p * 8 + idd) * 128 + e)
                       : *(const unsigned*)(comp_emb + (bs * 16 + 2 * n + 1) * 128 + e);
      } else v = 0u;
      *(unsigned*)(X + p * 328 + e0) = v;
    }
    __syncthreads();

    f32x4 acc[2];
    acc[0] = (f32x4){0.f,0.f,0.f,0.f}; acc[1] = (f32x4){0.f,0.f,0.f,0.f};
    for (int ks = 0; ks < 10; ++ks) {
      int kq = ks * 32 + quad * 8;
      bf16x8 a = *(const bf16x8*)(X + l15 * 328 + kq);
#pragma unroll
      for (int t2 = 0; t2 < 2; ++t2) {
        int nt = 2 * wv + t2;
        bf16x8 b = *(const bf16x8*)(Wt + (nt * 16 + l15) * 328 + kq);
        acc[t2] = __builtin_amdgcn_mfma_f32_16x16x32_bf16(a, b, acc[t2], 0, 0, 0);
      }
    }
    __syncthreads();
#pragma unroll
    for (int t2 = 0; t2 < 2; ++t2) {
      int nt = 2 * wv + t2;
#pragma unroll
      for (int rr = 0; rr < 4; ++rr) {
        int p = quad * 4 + rr;
        int col = nt * 16 + l15;
        VALS[(p * 8 + n) * 128 + col] = (bf16)tanhf_(acc[t2][rr] + recb[col]);
      }
    }
    __syncthreads();
  }

  for (int i = tid; i < 16 * 64; i += 256) {
    int p = i / 64, c2 = i % 64, e0 = 2 * c2;
    int bs = bs0 + p;
    int al = ALEN[p];
    unsigned v = (al == 0) ? *(const unsigned*)(comp_emb + (bs * 16) * 128 + e0)
                           : *(const unsigned*)(VALS + (p * 8 + (al - 1)) * 128 + e0);
    *(unsigned*)(stack_emb + bs * 128 + e0) = v;
  }
}

// =====================================================================
// Kernel 3: persistent 3x 2-layer masked LSTM, XCD-colocated h exchange.
// Base = round-3 kernel (best score, 1888us; counter barrier + COH path).
//
// THIS ROUND: MEASUREMENT.  Five theories falsified (serialized loads r1,
// MALL data path r3, RMW contention r6, serialized poll r8, DVFS r9);
// phase pinned at ~12.5us vs ~2.5us budget.  Instrument the heavy role
// (L=2, LAYER=1, u0=0) with s_memrealtime (100MHz):
//   t_bar = sum of (barrier arrival -> poll success) per phase
//   t_ld  = sum of the vmcnt(0) drain after the batched h-loads
// Export via counter channels (no host path needed):
//   t_bar -> (ticks/32) sc1 dword stores into dead comp_emb
//            => read as dWRITE_SIZE over the 27,416.7KB baseline
//            decode: t_bar_us_total ~ (5..10) * dKB
//   t_ld  -> (ticks/256) 32-way-conflicted ds_write_b32 by wave 0
//            => read as dSQ_LDS_BANK_CONFLICT over the exact 6,174,720
//            decode: t_ld_us_total ~ (0.04..0.08) * dCount
// Probes run after the loop, on dead memory, bounded (caps 8192/16384).
// =====================================================================
struct BarT { int cnt; int pad[31]; };

template<bool COH>
__device__ __forceinline__ bf16x8 hload(const bf16* p) {
  bf16x8 v;
  if constexpr (COH)
    asm volatile("global_load_dwordx4 %0, %1, off sc0" : "=v"(v) : "v"(p) : "memory");
  else
    asm volatile("global_load_dwordx4 %0, %1, off sc0 sc1" : "=v"(v) : "v"(p) : "memory");
  return v;
}

template<bool COH>
__device__ __forceinline__ void hstore(bf16* p, unsigned long long v) {
  if constexpr (COH)
    asm volatile("global_store_dwordx2 %0, %1, off" :: "v"(p), "v"(v) : "memory");
  else
    __hip_atomic_store((unsigned long long*)p, v, __ATOMIC_RELAXED, __HIP_MEMORY_SCOPE_AGENT);
}

template<int L, int LAYER, bool COH>
__device__ __forceinline__ void lstm_role(
    const float* W, const float* bias,
    const bf16* xsrc, const float* hist_tab, const int* hist_id,
    const int* lenp, bf16* h0w, bf16* h1w, BarT* bar, char* sm, int u0,
    char* pdst, int pch)
{
  constexpr int T   = (L == 0) ? STK : (L == 1) ? BUFF : HIST;
  constexpr int K   = (LAYER == 0) ? ((L == 2) ? 320 : 384) : 512;
  constexpr int KP  = K + 8;
  constexpr int Kxp = (LAYER == 0) ? ((L == 2) ? 64 : 128) : 256;
  constexpr int Tx  = (L == 0) ? STK : BUFF;

  const int tid = threadIdx.x;
  bf16*  Wt     = (bf16*)sm;                               // [128][KP]
  bf16*  hstage = (bf16*)(sm + 128 * KP * 2);              // [128][36]
  float* sb     = (float*)(sm + 128 * KP * 2 + 9216);      // [128]
  bf16*  Xa     = (bf16*)(sm + 128 * KP * 2 + 9216 + 512); // [128][72] (action L0)

  unsigned long long tbar = 0, tld = 0;

  // stage weight slice, transposed: Wt[cc][kk], cc = gate*32 + within
  for (int i = tid; i < K * 128; i += 256) {
    int kk = i >> 7, cc = i & 127;
    int col = (cc >> 5) * 256 + u0 + (cc & 31);
    bf16 v;
    if (LAYER == 0 && L == 2) {
      if (kk < 64) v = (kk < 50) ? (bf16)W[kk * 1024 + col] : (bf16)0.f;
      else         v = (bf16)W[(kk - 14) * 1024 + col];
    } else v = (bf16)W[kk * 1024 + col];
    Wt[cc * KP + kk] = v;
  }
  if (tid < 128) { int col = (tid >> 5) * 256 + u0 + (tid & 31); sb[tid] = bias[col]; }

  const int wv = tid >> 6, lane = tid & 63, l15 = lane & 15, quad = lane >> 4;
  int lenr[8];
#pragma unroll
  for (int mt = 0; mt < 2; ++mt)
#pragma unroll
    for (int rr = 0; rr < 4; ++rr)
      lenr[mt * 4 + rr] = lenp[32 * wv + 16 * mt + quad * 4 + rr];

  float cst[16], hst[16];
#pragma unroll
  for (int i = 0; i < 16; ++i) { cst[i] = 0.f; hst[i] = 0.f; }

  const int row0 = 32 * wv + l15;

  __syncthreads();

  for (int p = 0; p <= T; ++p) {
    const bool active = (LAYER == 0) ? (p < T) : (p >= 1);
    const int  t = (LAYER == 0) ? p : (p - 1);

    if (L == 2 && LAYER == 0 && active) {  // stage action x_t (50 -> 64 padded)
      for (int i = tid; i < 128 * 32; i += 256) {
        int row = i >> 5, e0 = 2 * (i & 31);
        unsigned v = 0u;
        if (e0 < 50) { int id = hist_id[row * 96 + t]; v = pack2(hist_tab + id * 50 + e0); }
        *(unsigned*)(Xa + row * 72 + e0) = v;
      }
    }
    __syncthreads();

    if (active) {
      const bf16* h0r = h0w + ((p - 1) & 1) * 32768;
      const bf16* h1r = h1w + (p & 1) * 32768;

      // ---- batch-issue ALL h-state loads for this phase ----
      bf16x8 hA[16];
#pragma unroll
      for (int hk = 0; hk < 8; ++hk)
#pragma unroll
        for (int mt = 0; mt < 2; ++mt)
          hA[hk * 2 + mt] = hload<COH>(h0r + (row0 + 16 * mt) * 256 + hk * 32 + quad * 8);
      bf16x8 hB[16];
      if (LAYER == 1) {
#pragma unroll
        for (int hk = 0; hk < 8; ++hk)
#pragma unroll
          for (int mt = 0; mt < 2; ++mt)
            hB[hk * 2 + mt] = hload<COH>(h1r + (row0 + 16 * mt) * 256 + hk * 32 + quad * 8);
      }

      f32x4 acc[2][8];
#pragma unroll
      for (int a1 = 0; a1 < 2; ++a1)
#pragma unroll
        for (int a2 = 0; a2 < 8; ++a2) acc[a1][a2] = (f32x4){0.f, 0.f, 0.f, 0.f};

      // ---- X part (layer0 only); overlaps the in-flight h loads ----
      if (LAYER == 0) {
#pragma unroll
        for (int ks = 0; ks < Kxp / 32; ++ks) {
          int kq = ks * 32 + quad * 8;
          bf16x8 a[2];
#pragma unroll
          for (int mt = 0; mt < 2; ++mt) {
            int row = row0 + 16 * mt;
            if (L == 2) a[mt] = *(const bf16x8*)(Xa + row * 72 + kq);
            else        a[mt] = *(const bf16x8*)(xsrc + (row * Tx + t) * 128 + kq);
          }
#pragma unroll
          for (int nt = 0; nt < 8; ++nt) {
            bf16x8 b = *(const bf16x8*)(Wt + (nt * 16 + l15) * KP + kq);
            acc[0][nt] = __builtin_amdgcn_mfma_f32_16x16x32_bf16(a[0], b, acc[0][nt], 0, 0, 0);
            acc[1][nt] = __builtin_amdgcn_mfma_f32_16x16x32_bf16(a[1], b, acc[1][nt], 0, 0, 0);
          }
        }
      }

      // drain the batch (t_ld measured on the probed role)
      unsigned long long tl0 = 0;
      if (pch && tid == 0) tl0 = __builtin_amdgcn_s_memrealtime();
      asm volatile("s_waitcnt vmcnt(0)" ::: "memory");
      __builtin_amdgcn_sched_barrier(0);
      if (pch && tid == 0) tld += __builtin_amdgcn_s_memrealtime() - tl0;

      // ---- H0 part (8 ksteps from hA) ----
      constexpr int HB0 = (LAYER == 0) ? Kxp : 0;
#pragma unroll
      for (int hk = 0; hk < 8; ++hk) {
        int kq = HB0 + hk * 32 + quad * 8;
#pragma unroll
        for (int nt = 0; nt < 8; ++nt) {
          bf16x8 b = *(const bf16x8*)(Wt + (nt * 16 + l15) * KP + kq);
          acc[0][nt] = __builtin_amdgcn_mfma_f32_16x16x32_bf16(hA[hk * 2 + 0], b, acc[0][nt], 0, 0, 0);
          acc[1][nt] = __builtin_amdgcn_mfma_f32_16x16x32_bf16(hA[hk * 2 + 1], b, acc[1][nt], 0, 0, 0);
        }
      }
      // ---- H1 part (layer1 only, 8 ksteps from hB) ----
      if (LAYER == 1) {
#pragma unroll
        for (int hk = 0; hk < 8; ++hk) {
          int kq = 256 + hk * 32 + quad * 8;
#pragma unroll
          for (int nt = 0; nt < 8; ++nt) {
            bf16x8 b = *(const bf16x8*)(Wt + (nt * 16 + l15) * KP + kq);
            acc[0][nt] = __builtin_amdgcn_mfma_f32_16x16x32_bf16(hB[hk * 2 + 0], b, acc[0][nt], 0, 0, 0);
            acc[1][nt] = __builtin_amdgcn_mfma_f32_16x16x32_bf16(hB[hk * 2 + 1], b, acc[1][nt], 0, 0, 0);
          }
        }
      }

      // gates: nt 0,1 = i ; 2,3 = j ; 4,5 = f ; 6,7 = o
#pragma unroll
      for (int mt = 0; mt < 2; ++mt)
#pragma unroll
        for (int g2 = 0; g2 < 2; ++g2)
#pragma unroll
          for (int rr = 0; rr < 4; ++rr) {
            int row = 32 * wv + 16 * mt + quad * 4 + rr;
            float zi = acc[mt][0 + g2][rr] + sb[(0 + g2) * 16 + l15];
            float zj = acc[mt][2 + g2][rr] + sb[(2 + g2) * 16 + l15];
            float zf = acc[mt][4 + g2][rr] + sb[(4 + g2) * 16 + l15];
            float zo = acc[mt][6 + g2][rr] + sb[(6 + g2) * 16 + l15];
            float ig = sigf(zi), jg = tanhf_(zj), fg = sigf(zf + 1.f), og = sigf(zo);
            int idx = mt * 8 + g2 * 4 + rr;
            float cn = cst[idx] * fg + ig * jg;
            float hn = tanhf_(cn) * og;
            bool mk = (t < lenr[mt * 4 + rr]);
            cst[idx] = mk ? cn : cst[idx];
            hst[idx] = mk ? hn : hst[idx];
            hstage[row * 36 + g2 * 16 + l15] = (bf16)hst[idx];
          }
    }
    __syncthreads();
    if (active) {
      bf16* dst = (LAYER == 0) ? (h0w + (p & 1) * 32768) : (h1w + ((p - 1) & 1) * 32768);
      for (int i = tid; i < 128 * 8; i += 256) {
        int row = i >> 3, c = i & 7;
        unsigned long long v = *(const unsigned long long*)(hstage + row * 36 + c * 4);
        hstore<COH>(dst + row * 256 + u0 + c * 4, v);
      }
    }
    // inter-block barrier (16 participants/LSTM), MALL counter path.
    // t_bar measured on the probed role: arrival -> poll success.
    if (p < T) {
      __syncthreads();
      if (tid == 0) {
        unsigned long long tb0 = 0;
        if (pch) tb0 = __builtin_amdgcn_s_memrealtime();
        __builtin_amdgcn_sched_barrier(0);
        const int target = 16 * (p + 1);
        int prev = __hip_atomic_fetch_add(&bar->cnt, 1, __ATOMIC_RELAXED, __HIP_MEMORY_SCOPE_AGENT);
        if (prev != target - 1) {
          while (__hip_atomic_load(&bar->cnt, __ATOMIC_RELAXED, __HIP_MEMORY_SCOPE_AGENT) < target) { }
        }
        __builtin_amdgcn_sched_barrier(0);
        if (pch) tbar += __builtin_amdgcn_s_memrealtime() - tb0;
      }
      __syncthreads();
    }
  }

  // ---- export probes (dead memory, bounded; after all sync) ----
  if (pch) {
    if (tid == 0) {
      unsigned long long n = tbar >> 5;          // ticks/32
      if (n > 8192) n = 8192;
      for (unsigned long long i = 0; i < n; ++i) {
        char* ap = pdst + ((i & 8191) << 8);     // stride 256B in dead region
        unsigned v = (unsigned)i;
        asm volatile("global_store_dword %0, %1, off sc0 sc1" :: "v"(ap), "v"(v) : "memory");
      }
      asm volatile("s_waitcnt vmcnt(0)" ::: "memory");
    }
    if (tid < 64) {
      int n2 = (tid == 0) ? (int)(tld >> 8) : 0; // ticks/256
      n2 = __shfl(n2, 0);
      if (n2 > 16384) n2 = 16384;
      volatile unsigned* lp = (volatile unsigned*)((char*)hstage + tid * 128); // all bank 0
      for (int i = 0; i < n2; ++i) *lp = (unsigned)i;
    }
  }
}

__global__ __launch_bounds__(256, 1) void k_lstm(
    const float* sW0, const float* sb0, const float* sW1, const float* sb1,
    const float* bW0, const float* bb0, const float* bW1, const float* bb1,
    const float* aW0, const float* ab0, const float* aW1, const float* ab1,
    const bf16* stack_emb, const bf16* buff_emb, const float* hist_tab, const int* hist_id,
    const int* len_s, const int* len_b, const int* len_a,
    bf16* h0buf, bf16* h1buf, BarT* bars, BarT* cbars, int* taken, int* xcctab, int* probes,
    bf16* probe_dst)
{
  __shared__ __align__(16) char sm[143872];
  __shared__ int s_role[3];
  const int tid = threadIdx.x;

  if (tid == 0) {
    // HW_REG_XCC_ID: id=20, offset=0, size=4 -> imm = 20 | (3<<11) = 6164
    int xcc = __builtin_amdgcn_s_getreg(6164) & 0xF;
    int l = -1, r = -1;
    // primary: claim a slot of THIS XCD's LSTM (bounded CAS scan)
    if (xcc < 3) {
      int st = blockIdx.x & 15;
      for (int ii = 0; ii < 16 && l < 0; ++ii) {
        int i = (st + ii) & 15;
        int exp0 = 0;
        if (__hip_atomic_compare_exchange_strong(&taken[xcc * 16 + i], &exp0, 1,
              __ATOMIC_RELAXED, __ATOMIC_RELAXED, __HIP_MEMORY_SCOPE_AGENT)) { l = xcc; r = i; }
      }
    }
    if (l < 0) {
      // timed wait (~100us), then scavenge ANY unclaimed slot (bounded)
      unsigned long long t0 = __builtin_amdgcn_s_memrealtime();  // 100 MHz
      while (__builtin_amdgcn_s_memrealtime() - t0 < 10000ULL) __builtin_amdgcn_s_sleep(16);
      for (int i = 0; i < 48 && l < 0; ++i) {
        int exp0 = 0;
        if (__hip_atomic_compare_exchange_strong(&taken[i], &exp0, 1,
              __ATOMIC_RELAXED, __ATOMIC_RELAXED, __HIP_MEMORY_SCOPE_AGENT)) { l = i >> 4; r = i & 15; }
      }
    }
    s_role[0] = l; s_role[1] = r; s_role[2] = 0;
    if (l >= 0) {
      // publish XCD id (MALL) + probe token (PLAIN store -> stays in my L2)
      __hip_atomic_store(&xcctab[l * 16 + r], xcc + 1, __ATOMIC_RELAXED, __HIP_MEMORY_SCOPE_AGENT);
      int* pp = &probes[l * 16 + r];
      int tok = r + 1;
      asm volatile("global_store_dword %0, %1, off" :: "v"(pp), "v"(tok) : "memory");
      asm volatile("s_waitcnt vmcnt(0)" ::: "memory");
      // one-time claim barrier (MALL path; terminates: all 48 slots claimed)
      __hip_atomic_fetch_add(&cbars[l].cnt, 1, __ATOMIC_RELAXED, __HIP_MEMORY_SCOPE_AGENT);
      while (__hip_atomic_load(&cbars[l].cnt, __ATOMIC_RELAXED, __HIP_MEMORY_SCOPE_AGENT) < 16)
        __builtin_amdgcn_s_sleep(1);
      // COH = (all 16 on my physical XCD) AND (probe visibility via L2 path)
      int myx = xcc + 1, coh = 1;
      for (int i = 0; i < 16; ++i)
        coh &= (__hip_atomic_load(&xcctab[l * 16 + i], __ATOMIC_RELAXED, __HIP_MEMORY_SCOPE_AGENT) == myx);
      for (int i = 0; i < 16; ++i) {
        int* qp = &probes[l * 16 + i];
        int pv;
        asm volatile("global_load_dword %0, %1, off sc0" : "=v"(pv) : "v"(qp) : "memory");
        asm volatile("s_waitcnt vmcnt(0)" ::: "memory");
        coh &= (pv == i + 1);
      }
      s_role[2] = coh;
    }
  }
  __syncthreads();

  const int l = s_role[0];
  if (l < 0) return;
  const int rid = s_role[1], coh = s_role[2];
  const int layer = rid >> 3;
  const int u0    = (rid & 7) * 32;

  BarT* bar = bars + l;
  bf16* h0w = h0buf + l * 2 * 32768;  // [2][128][256]
  bf16* h1w = h1buf + l * 2 * 32768;

  const float *W0_, *b0_, *W1_, *b1_; const bf16* xs_; const int* lenp_;
  if (l == 0)      { W0_ = sW0; b0_ = sb0; W1_ = sW1; b1_ = sb1; xs_ = stack_emb; lenp_ = len_s; }
  else if (l == 1) { W0_ = bW0; b0_ = bb0; W1_ = bW1; b1_ = bb1; xs_ = buff_emb;  lenp_ = len_b; }
  else             { W0_ = aW0; b0_ = ab0; W1_ = aW1; b1_ = ab1; xs_ = nullptr;   lenp_ = len_a; }
  const float* W  = layer ? W1_ : W0_;
  const float* bi = layer ? b1_ : b0_;

  char* pd = (char*)probe_dst;
  const int pch = (l == 2 && layer == 1 && u0 == 0) ? 1 : 0;

  switch (l * 4 + layer * 2 + coh) {
    case  0: lstm_role<0, 0, false>(W, bi, xs_, hist_tab, hist_id, lenp_, h0w, h1w, bar, sm, u0, pd, pch); break;
    case  1: lstm_role<0, 0, true >(W, bi, xs_, hist_tab, hist_id, lenp_, h0w, h1w, bar, sm, u0, pd, pch); break;
    case  2: lstm_role<0, 1, false>(W, bi, xs_, hist_tab, hist_id, lenp_, h0w, h1w, bar, sm, u0, pd, pch); break;
    case  3: lstm_role<0, 1, true >(W, bi, xs_, hist_tab, hist_id, lenp_, h0w, h1w, bar, sm, u0, pd, pch); break;
    case  4: lstm_role<1, 0, false>(W, bi, xs_, hist_tab, hist_id, lenp_, h0w, h1w, bar, sm, u0, pd, pch); break;
    case  5: lstm_role<1, 0, true >(W, bi, xs_, hist_tab, hist_id, lenp_, h0w, h1w, bar, sm, u0, pd, pch); break;
    case  6: lstm_role<1, 1, false>(W, bi, xs_, hist_tab, hist_id, lenp_, h0w, h1w, bar, sm, u0, pd, pch); break;
    case  7: lstm_role<1, 1, true >(W, bi, xs_, hist_tab, hist_id, lenp_, h0w, h1w, bar, sm, u0, pd, pch); break;
    case  8: lstm_role<2, 0, false>(W, bi, xs_, hist_tab, hist_id, lenp_, h0w, h1w, bar, sm, u0, pd, pch); break;
    case  9: lstm_role<2, 0, true >(W, bi, xs_, hist_tab, hist_id, lenp_, h0w, h1w, bar, sm, u0, pd, pch); break;
    case 10: lstm_role<2, 1, false>(W, bi, xs_, hist_tab, hist_id, lenp_, h0w, h1w, bar, sm, u0, pd, pch); break;
    case 11: lstm_role<2, 1, true >(W, bi, xs_, hist_tab, hist_id, lenp_, h0w, h1w, bar, sm, u0, pd, pch); break;
  }
}

// =====================================================================
// Kernel 4: out = concat(h_s,h_b,h_a) @ fW + fb
// =====================================================================
__global__ __launch_bounds__(128) void k_final(
    const bf16* h1buf, const float* fW, const float* fb, float* out)
{
  __shared__ float hs[768];
  const int b = blockIdx.x, tid = threadIdx.x;
  for (int i = tid; i < 768; i += 128) {
    int L = i >> 8, u = i & 255;
    hs[i] = (float)h1buf[(L * 2 + 1) * 32768 + b * 256 + u];  // final parity = 1 (T even)
  }
  __syncthreads();
  if (tid < NOUT) {
    float acc = fb[tid];
    for (int u = 0; u < 768; ++u) acc += hs[u] * fW[u * NOUT + tid];
    out[b * NOUT + tid] = acc;
  }
}

// =====================================================================
extern "C" void kernel_launch(void* const* d_in, const int* in_sizes, int n_in,
                              void* d_out, int out_size, void* d_ws, size_t ws_size,
                              hipStream_t stream)
{
  (void)in_sizes; (void)n_in; (void)out_size; (void)ws_size;
  char* ws = (char*)d_ws;
  BarT* bars   = (BarT*)ws;                  // 3*128 = 384 (region 512)
  BarT* cbars  = (BarT*)(ws + 512);          // 3*128 = 384 (region 512)
  int*  taken  = (int*)(ws + 1024);          // 48 ints (1024..1216)
  int*  xcctab = (int*)(ws + 1280);          // 48 ints (1280..1472)
  int*  probes = (int*)(ws + 1536);          // 48 ints (1536..1728, region to 2048)
  bf16* h0buf  = (bf16*)(ws + 2048);         // 3*2*128*256*2 = 393216
  bf16* h1buf  = (bf16*)(ws + 2048 + 393216);                // 393216 -> ends 788480
  bf16* comp_emb  = (bf16*)(ws + 788480);                    // 98304*128*2 = 25165824
  bf16* buff_emb  = (bf16*)(ws + 788480 + 25165824);         // 8192*128*2  = 2097152
  bf16* stack_emb = (bf16*)(ws + 788480 + 25165824 + 2097152); // 6144*128*2 = 1572864

  hipMemsetAsync(ws, 0, 788480, stream);  // control block + h0/h1 init state

  k_emb<<<1664, 256, 0, stream>>>(
      (const int*)d_in[0], (const int*)d_in[1], (const int*)d_in[2], (const int*)d_in[3],
      (const float*)d_in[13], (const float*)d_in[10], (const float*)d_in[14], (const float*)d_in[15],
      comp_emb, buff_emb);

  k_compose<<<384, 256, 0, stream>>>(
      (const int*)d_in[2], (const int*)d_in[4], (const int*)d_in[5],
      comp_emb, (const float*)d_in[11], (const float*)d_in[16], (const float*)d_in[17],
      stack_emb);

  k_lstm<<<256, 256, 0, stream>>>(
      (const float*)d_in[18], (const float*)d_in[19], (const float*)d_in[20], (const float*)d_in[21],
      (const float*)d_in[22], (const float*)d_in[23], (const float*)d_in[24], (const float*)d_in[25],
      (const float*)d_in[26], (const float*)d_in[27], (const float*)d_in[28], (const float*)d_in[29],
      stack_emb, buff_emb, (const float*)d_in[12], (const int*)d_in[6],
      (const int*)d_in[7], (const int*)d_in[8], (const int*)d_in[9],
      h0buf, h1buf, bars, cbars, taken, xcctab, probes, comp_emb);

  k_final<<<128, 128, 0, stream>>>(h1buf, (const float*)d_in[30], (const float*)d_in[31],
                                   (float*)d_out);
}

// Round 11
// 1701.614 us; speedup vs baseline: 1.1597x; 1.1597x over previous
//
#include <hip/hip_runtime.h>

// ---------------- problem constants ----------------
#define BB    128
#define BUFF  64
#define STK   48
#define NCOMP 8
#define HIST  96
#define WDIM  300
#define POSD  50
#define CAD   50
#define HAD   50
#define FC    128
#define UU    256
#define NOUT  82

typedef __bf16 bf16;
typedef __attribute__((ext_vector_type(8))) __bf16 bf16x8;
typedef __attribute__((ext_vector_type(4))) float   f32x4;

__device__ __forceinline__ float sigf(float x)   { return 1.f / (1.f + __expf(-x)); }
__device__ __forceinline__ float tanhf_(float x) { return 1.f - 2.f / (1.f + __expf(2.f * x)); }

// pack two consecutive fp32 values as two bf16 in one u32
__device__ __forceinline__ unsigned pack2(const float* p) {
  union { unsigned u; bf16 h[2]; } r;
  r.h[0] = (bf16)p[0]; r.h[1] = (bf16)p[1];
  return r.u;
}

// =====================================================================
// Kernel 1: embedding MLP.  rows 0..98303 = comp, 98304..106495 = buff.
// out = relu(concat(w_emb[word](300), p_emb[pos](50)) @ emb_W(350x128) + b)
// =====================================================================
__global__ __launch_bounds__(256) void k_emb(
    const int* bw, const int* bp, const int* cw, const int* cp,
    const float* w_emb, const float* p_emb, const float* embW, const float* embB,
    bf16* comp_emb, bf16* buff_emb)
{
  __shared__ __align__(16) char sm[138752];
  bf16*  A  = (bf16*)sm;                    // [64][360]
  bf16*  Wt = (bf16*)(sm + 46080);          // [128][360] (transposed: [n][k])
  float* sb = (float*)(sm + 46080 + 92160); // [128]

  const int tid = threadIdx.x;
  const int r0  = blockIdx.x * 64;

  // stage A rows (word||pos||0), converting fp32 -> bf16, 2 per u32
  for (int i = tid; i < 64 * 176; i += 256) {
    int m = i / 176, c2 = i % 176, e0 = 2 * c2;
    int r = r0 + m;
    unsigned v;
    if (e0 < 300) {
      int word = (r < 98304) ? cw[r] : bw[r - 98304];
      v = pack2(w_emb + word * 300 + e0);
    } else if (e0 < 350) {
      int pos = (r < 98304) ? cp[r] : bp[r - 98304];
      v = pack2(p_emb + pos * 50 + (e0 - 300));
    } else v = 0u;
    *(unsigned*)(A + m * 360 + e0) = v;
  }
  // stage W transposed (fp32 -> bf16)
  for (int i = tid; i < 350 * 128; i += 256) {
    int k = i >> 7, n = i & 127;
    Wt[n * 360 + k] = (bf16)embW[i];
  }
  // zero k=350,351 in Wt
  { int i = tid; if (i < 256) { int n = i >> 1; Wt[n * 360 + 350 + (i & 1)] = (bf16)0.f; } }
  if (tid < 128) sb[tid] = embB[tid];
  __syncthreads();

  const int wv = tid >> 6, lane = tid & 63, l15 = lane & 15, quad = lane >> 4;
  f32x4 acc[8];
#pragma unroll
  for (int i = 0; i < 8; ++i) acc[i] = (f32x4){0.f, 0.f, 0.f, 0.f};

  const bf16* Arow = A + (wv * 16 + l15) * 360;
  for (int ks = 0; ks < 11; ++ks) {
    int kq = ks * 32 + quad * 8;
    bf16x8 a = *(const bf16x8*)(Arow + kq);
#pragma unroll
    for (int nt = 0; nt < 8; ++nt) {
      bf16x8 b = *(const bf16x8*)(Wt + (nt * 16 + l15) * 360 + kq);
      acc[nt] = __builtin_amdgcn_mfma_f32_16x16x32_bf16(a, b, acc[nt], 0, 0, 0);
    }
  }
#pragma unroll
  for (int nt = 0; nt < 8; ++nt)
#pragma unroll
    for (int rr = 0; rr < 4; ++rr) {
      int row = wv * 16 + quad * 4 + rr;
      int n   = nt * 16 + l15;
      float z = fmaxf(acc[nt][rr] + sb[n], 0.f);
      int r = r0 + row;
      bf16 o = (bf16)z;
      if (r < 98304) comp_emb[r * 128 + n] = o;
      else           buff_emb[(r - 98304) * 128 + n] = o;
    }
}

// =====================================================================
// Kernel 2: compose.  16 (b,s) pairs per block, 8 sequential steps in LDS.
// =====================================================================
__global__ __launch_bounds__(256) void k_compose(
    const int* cw, const int* caid, const int* calen,
    const bf16* comp_emb, const float* ca_emb, const float* recW, const float* recB,
    bf16* stack_emb)
{
  __shared__ __align__(16) char sm[129344];
  bf16*  Wt   = (bf16*)sm;              // [128][328]
  bf16*  X    = (bf16*)(sm + 83968);    // [16][328]
  bf16*  VALS = (bf16*)(sm + 94464);    // [16][8][128]
  float* recb = (float*)(sm + 127232);  // [128]
  int*   IH   = (int*)(sm + 127744);    // [16][8]
  int*   ID   = (int*)(sm + 128256);
  int*   AN   = (int*)(sm + 128768);
  int*   ALEN = (int*)(sm + 129280);    // [16]

  const int tid = threadIdx.x;
  const int bs0 = blockIdx.x * 16;

  for (int i = tid; i < 306 * 128; i += 256) {
    int k = i >> 7, n = i & 127;
    Wt[n * 328 + k] = (bf16)recW[i];
  }
  for (int i = tid; i < 128 * 22; i += 256) {  // zero pad rows 306..327
    int n = i / 22, k = 306 + i % 22;
    Wt[n * 328 + k] = (bf16)0.f;
  }
  if (tid < 128) recb[tid] = recB[tid];
  if (tid < 16) {
    int bs = bs0 + tid;
    int hid[8], did[8];
#pragma unroll
    for (int m = 0; m < 8; ++m) { hid[m] = cw[bs * 16 + 2 * m]; did[m] = cw[bs * 16 + 2 * m + 1]; }
    for (int n = 0; n < 8; ++n) {
      int ih = -1, idd = -1;
      for (int m = 0; m < n; ++m) { if (hid[m] == hid[n]) ih = m; if (hid[m] == did[n]) idd = m; }
      IH[tid * 8 + n] = ih; ID[tid * 8 + n] = idd; AN[tid * 8 + n] = caid[bs * 8 + n];
    }
    ALEN[tid] = calen[bs];
  }
  __syncthreads();

  const int wv = tid >> 6, lane = tid & 63, l15 = lane & 15, quad = lane >> 4;

  for (int n = 0; n < 8; ++n) {
    // stage X = [head_e(128) | act(50) | dep_e(128) | 0 pad] per pair
    for (int i = tid; i < 16 * 160; i += 256) {
      int p = i / 160, c2 = i % 160, e0 = 2 * c2;
      int bs = bs0 + p;
      unsigned v;
      if (e0 < 128) {
        int ih = IH[p * 8 + n];
        v = (ih >= 0) ? *(const unsigned*)(VALS + (p * 8 + ih) * 128 + e0)
                      : *(const unsigned*)(comp_emb + (bs * 16 + 2 * n) * 128 + e0);
      } else if (e0 < 178) {
        v = pack2(ca_emb + AN[p * 8 + n] * 50 + (e0 - 128));
      } else if (e0 < 306) {
        int e = e0 - 178;
        int idd = ID[p * 8 + n];
        v = (idd >= 0) ? *(const unsigned*)(VALS + (p * 8 + idd) * 128 + e)
                       : *(const unsigned*)(comp_emb + (bs * 16 + 2 * n + 1) * 128 + e);
      } else v = 0u;
      *(unsigned*)(X + p * 328 + e0) = v;
    }
    __syncthreads();

    f32x4 acc[2];
    acc[0] = (f32x4){0.f,0.f,0.f,0.f}; acc[1] = (f32x4){0.f,0.f,0.f,0.f};
    for (int ks = 0; ks < 10; ++ks) {
      int kq = ks * 32 + quad * 8;
      bf16x8 a = *(const bf16x8*)(X + l15 * 328 + kq);
#pragma unroll
      for (int t2 = 0; t2 < 2; ++t2) {
        int nt = 2 * wv + t2;
        bf16x8 b = *(const bf16x8*)(Wt + (nt * 16 + l15) * 328 + kq);
        acc[t2] = __builtin_amdgcn_mfma_f32_16x16x32_bf16(a, b, acc[t2], 0, 0, 0);
      }
    }
    __syncthreads();
#pragma unroll
    for (int t2 = 0; t2 < 2; ++t2) {
      int nt = 2 * wv + t2;
#pragma unroll
      for (int rr = 0; rr < 4; ++rr) {
        int p = quad * 4 + rr;
        int col = nt * 16 + l15;
        VALS[(p * 8 + n) * 128 + col] = (bf16)tanhf_(acc[t2][rr] + recb[col]);
      }
    }
    __syncthreads();
  }

  for (int i = tid; i < 16 * 64; i += 256) {
    int p = i / 64, c2 = i % 64, e0 = 2 * c2;
    int bs = bs0 + p;
    int al = ALEN[p];
    unsigned v = (al == 0) ? *(const unsigned*)(comp_emb + (bs * 16) * 128 + e0)
                           : *(const unsigned*)(VALS + (p * 8 + (al - 1)) * 128 + e0);
    *(unsigned*)(stack_emb + bs * 128 + e0) = v;
  }
}

// =====================================================================
// Kernel 3: persistent 3x 2-layer masked LSTM, XCD-colocated h exchange.
// Base = round-3 (best, 1888us).  r10's probe DECODE: for the heaviest
// block, barrier wait ~1.1us/phase (dWRITE 21.5KB) and h-load drain
// ~0.9us/phase (dCONFLICT ~2k) -- i.e. ~10.5 of 12.5us/phase is INSIDE
// the block's active region; the probed block is the straggler.  At
// 256 threads / 143KB LDS = 1 block/CU = 1 wave/SIMD there is ZERO TLP:
// every ds_read (~120cy), transcendental and vmcnt is latency-exposed
// (per-active-CU VALUBusy ~15%, MfmaUtil ~8%, ~77% stall).  This also
// explains the five null rounds (r1/r3/r6/r8/r9 each shaved ~1us terms).
//
// THIS ROUND: 2 waves/SIMD.  512 threads/block (8 waves); each wave owns
// 16 rows (row0 = 16*wv + l15) instead of 32: single A-frag per k-step,
// acc[8], hA[8]/hB[8], staging loops stride 512.  Per-wave chains halve
// AND a co-resident wave fills stall slots.  Same barrier, same COH path,
// same claim protocol.  LDS unchanged -> still 1 block/CU.
// =====================================================================
struct BarT { int cnt; int pad[31]; };

template<bool COH>
__device__ __forceinline__ bf16x8 hload(const bf16* p) {
  bf16x8 v;
  if constexpr (COH)
    asm volatile("global_load_dwordx4 %0, %1, off sc0" : "=v"(v) : "v"(p) : "memory");
  else
    asm volatile("global_load_dwordx4 %0, %1, off sc0 sc1" : "=v"(v) : "v"(p) : "memory");
  return v;
}

template<bool COH>
__device__ __forceinline__ void hstore(bf16* p, unsigned long long v) {
  if constexpr (COH)
    asm volatile("global_store_dwordx2 %0, %1, off" :: "v"(p), "v"(v) : "memory");
  else
    __hip_atomic_store((unsigned long long*)p, v, __ATOMIC_RELAXED, __HIP_MEMORY_SCOPE_AGENT);
}

template<int L, int LAYER, bool COH>
__device__ __forceinline__ void lstm_role(
    const float* W, const float* bias,
    const bf16* xsrc, const float* hist_tab, const int* hist_id,
    const int* lenp, bf16* h0w, bf16* h1w, BarT* bar, char* sm, int u0)
{
  constexpr int T   = (L == 0) ? STK : (L == 1) ? BUFF : HIST;
  constexpr int K   = (LAYER == 0) ? ((L == 2) ? 320 : 384) : 512;
  constexpr int KP  = K + 8;
  constexpr int Kxp = (LAYER == 0) ? ((L == 2) ? 64 : 128) : 256;
  constexpr int Tx  = (L == 0) ? STK : BUFF;

  const int tid = threadIdx.x;
  bf16*  Wt     = (bf16*)sm;                               // [128][KP]
  bf16*  hstage = (bf16*)(sm + 128 * KP * 2);              // [128][36]
  float* sb     = (float*)(sm + 128 * KP * 2 + 9216);      // [128]
  bf16*  Xa     = (bf16*)(sm + 128 * KP * 2 + 9216 + 512); // [128][72] (action L0)

  // stage weight slice, transposed: Wt[cc][kk], cc = gate*32 + within
  for (int i = tid; i < K * 128; i += 512) {
    int kk = i >> 7, cc = i & 127;
    int col = (cc >> 5) * 256 + u0 + (cc & 31);
    bf16 v;
    if (LAYER == 0 && L == 2) {
      if (kk < 64) v = (kk < 50) ? (bf16)W[kk * 1024 + col] : (bf16)0.f;
      else         v = (bf16)W[(kk - 14) * 1024 + col];
    } else v = (bf16)W[kk * 1024 + col];
    Wt[cc * KP + kk] = v;
  }
  if (tid < 128) { int col = (tid >> 5) * 256 + u0 + (tid & 31); sb[tid] = bias[col]; }

  const int wv = tid >> 6, lane = tid & 63, l15 = lane & 15, quad = lane >> 4;
  // 8 waves: wave wv owns rows 16*wv .. 16*wv+15
  const int row0 = 16 * wv + l15;
  int lenr[4];
#pragma unroll
  for (int rr = 0; rr < 4; ++rr)
    lenr[rr] = lenp[16 * wv + quad * 4 + rr];

  float cst[8], hst[8];
#pragma unroll
  for (int i = 0; i < 8; ++i) { cst[i] = 0.f; hst[i] = 0.f; }

  __syncthreads();

  for (int p = 0; p <= T; ++p) {
    const bool active = (LAYER == 0) ? (p < T) : (p >= 1);
    const int  t = (LAYER == 0) ? p : (p - 1);

    if (L == 2 && LAYER == 0 && active) {  // stage action x_t (50 -> 64 padded)
      for (int i = tid; i < 128 * 32; i += 512) {
        int row = i >> 5, e0 = 2 * (i & 31);
        unsigned v = 0u;
        if (e0 < 50) { int id = hist_id[row * 96 + t]; v = pack2(hist_tab + id * 50 + e0); }
        *(unsigned*)(Xa + row * 72 + e0) = v;
      }
    }
    __syncthreads();

    if (active) {
      const bf16* h0r = h0w + ((p - 1) & 1) * 32768;
      const bf16* h1r = h1w + (p & 1) * 32768;

      // ---- batch-issue ALL h-state loads for this phase ----
      bf16x8 hA[8];
#pragma unroll
      for (int hk = 0; hk < 8; ++hk)
        hA[hk] = hload<COH>(h0r + row0 * 256 + hk * 32 + quad * 8);
      bf16x8 hB[8];
      if (LAYER == 1) {
#pragma unroll
        for (int hk = 0; hk < 8; ++hk)
          hB[hk] = hload<COH>(h1r + row0 * 256 + hk * 32 + quad * 8);
      }

      f32x4 acc[8];
#pragma unroll
      for (int a2 = 0; a2 < 8; ++a2) acc[a2] = (f32x4){0.f, 0.f, 0.f, 0.f};

      // ---- X part (layer0 only); overlaps the in-flight h loads ----
      if (LAYER == 0) {
#pragma unroll
        for (int ks = 0; ks < Kxp / 32; ++ks) {
          int kq = ks * 32 + quad * 8;
          bf16x8 a;
          if (L == 2) a = *(const bf16x8*)(Xa + row0 * 72 + kq);
          else        a = *(const bf16x8*)(xsrc + (row0 * Tx + t) * 128 + kq);
#pragma unroll
          for (int nt = 0; nt < 8; ++nt) {
            bf16x8 b = *(const bf16x8*)(Wt + (nt * 16 + l15) * KP + kq);
            acc[nt] = __builtin_amdgcn_mfma_f32_16x16x32_bf16(a, b, acc[nt], 0, 0, 0);
          }
        }
      }

      // drain the batch; sched_barrier keeps MFMAs from hoisting above it
      asm volatile("s_waitcnt vmcnt(0)" ::: "memory");
      __builtin_amdgcn_sched_barrier(0);

      // ---- H0 part (8 ksteps from hA) ----
      constexpr int HB0 = (LAYER == 0) ? Kxp : 0;
#pragma unroll
      for (int hk = 0; hk < 8; ++hk) {
        int kq = HB0 + hk * 32 + quad * 8;
#pragma unroll
        for (int nt = 0; nt < 8; ++nt) {
          bf16x8 b = *(const bf16x8*)(Wt + (nt * 16 + l15) * KP + kq);
          acc[nt] = __builtin_amdgcn_mfma_f32_16x16x32_bf16(hA[hk], b, acc[nt], 0, 0, 0);
        }
      }
      // ---- H1 part (layer1 only, 8 ksteps from hB) ----
      if (LAYER == 1) {
#pragma unroll
        for (int hk = 0; hk < 8; ++hk) {
          int kq = 256 + hk * 32 + quad * 8;
#pragma unroll
          for (int nt = 0; nt < 8; ++nt) {
            bf16x8 b = *(const bf16x8*)(Wt + (nt * 16 + l15) * KP + kq);
            acc[nt] = __builtin_amdgcn_mfma_f32_16x16x32_bf16(hB[hk], b, acc[nt], 0, 0, 0);
          }
        }
      }

      // gates: nt 0,1 = i ; 2,3 = j ; 4,5 = f ; 6,7 = o
#pragma unroll
      for (int g2 = 0; g2 < 2; ++g2)
#pragma unroll
        for (int rr = 0; rr < 4; ++rr) {
          int row = 16 * wv + quad * 4 + rr;
          float zi = acc[0 + g2][rr] + sb[(0 + g2) * 16 + l15];
          float zj = acc[2 + g2][rr] + sb[(2 + g2) * 16 + l15];
          float zf = acc[4 + g2][rr] + sb[(4 + g2) * 16 + l15];
          float zo = acc[6 + g2][rr] + sb[(6 + g2) * 16 + l15];
          float ig = sigf(zi), jg = tanhf_(zj), fg = sigf(zf + 1.f), og = sigf(zo);
          int idx = g2 * 4 + rr;
          float cn = cst[idx] * fg + ig * jg;
          float hn = tanhf_(cn) * og;
          bool mk = (t < lenr[rr]);
          cst[idx] = mk ? cn : cst[idx];
          hst[idx] = mk ? hn : hst[idx];
          hstage[row * 36 + g2 * 16 + l15] = (bf16)hst[idx];
        }
    }
    __syncthreads();
    if (active) {
      bf16* dst = (LAYER == 0) ? (h0w + (p & 1) * 32768) : (h1w + ((p - 1) & 1) * 32768);
      for (int i = tid; i < 128 * 8; i += 512) {
        int row = i >> 3, c = i & 7;
        unsigned long long v = *(const unsigned long long*)(hstage + row * 36 + c * 4);
        hstore<COH>(dst + row * 256 + u0 + c * 4, v);
      }
    }
    // inter-block barrier (16 participants/LSTM), MALL counter path
    // (round-3-proven).  __syncthreads drains vmcnt before arrival.
    if (p < T) {
      __syncthreads();
      if (tid == 0) {
        __builtin_amdgcn_sched_barrier(0);
        const int target = 16 * (p + 1);
        int prev = __hip_atomic_fetch_add(&bar->cnt, 1, __ATOMIC_RELAXED, __HIP_MEMORY_SCOPE_AGENT);
        if (prev != target - 1) {
          while (__hip_atomic_load(&bar->cnt, __ATOMIC_RELAXED, __HIP_MEMORY_SCOPE_AGENT) < target) { }
        }
        __builtin_amdgcn_sched_barrier(0);
      }
      __syncthreads();
    }
  }
}

__global__ __launch_bounds__(512, 1) void k_lstm(
    const float* sW0, const float* sb0, const float* sW1, const float* sb1,
    const float* bW0, const float* bb0, const float* bW1, const float* bb1,
    const float* aW0, const float* ab0, const float* aW1, const float* ab1,
    const bf16* stack_emb, const bf16* buff_emb, const float* hist_tab, const int* hist_id,
    const int* len_s, const int* len_b, const int* len_a,
    bf16* h0buf, bf16* h1buf, BarT* bars, BarT* cbars, int* taken, int* xcctab, int* probes)
{
  __shared__ __align__(16) char sm[143872];
  __shared__ int s_role[3];
  const int tid = threadIdx.x;

  if (tid == 0) {
    // HW_REG_XCC_ID: id=20, offset=0, size=4 -> imm = 20 | (3<<11) = 6164
    int xcc = __builtin_amdgcn_s_getreg(6164) & 0xF;
    int l = -1, r = -1;
    // primary: claim a slot of THIS XCD's LSTM (bounded CAS scan)
    if (xcc < 3) {
      int st = blockIdx.x & 15;
      for (int ii = 0; ii < 16 && l < 0; ++ii) {
        int i = (st + ii) & 15;
        int exp0 = 0;
        if (__hip_atomic_compare_exchange_strong(&taken[xcc * 16 + i], &exp0, 1,
              __ATOMIC_RELAXED, __ATOMIC_RELAXED, __HIP_MEMORY_SCOPE_AGENT)) { l = xcc; r = i; }
      }
    }
    if (l < 0) {
      // timed wait (~100us), then scavenge ANY unclaimed slot (bounded)
      unsigned long long t0 = __builtin_amdgcn_s_memrealtime();  // 100 MHz
      while (__builtin_amdgcn_s_memrealtime() - t0 < 10000ULL) __builtin_amdgcn_s_sleep(16);
      for (int i = 0; i < 48 && l < 0; ++i) {
        int exp0 = 0;
        if (__hip_atomic_compare_exchange_strong(&taken[i], &exp0, 1,
              __ATOMIC_RELAXED, __ATOMIC_RELAXED, __HIP_MEMORY_SCOPE_AGENT)) { l = i >> 4; r = i & 15; }
      }
    }
    s_role[0] = l; s_role[1] = r; s_role[2] = 0;
    if (l >= 0) {
      // publish XCD id (MALL) + probe token (PLAIN store -> stays in my L2)
      __hip_atomic_store(&xcctab[l * 16 + r], xcc + 1, __ATOMIC_RELAXED, __HIP_MEMORY_SCOPE_AGENT);
      int* pp = &probes[l * 16 + r];
      int tok = r + 1;
      asm volatile("global_store_dword %0, %1, off" :: "v"(pp), "v"(tok) : "memory");
      asm volatile("s_waitcnt vmcnt(0)" ::: "memory");
      // one-time claim barrier (MALL path; terminates: all 48 slots claimed)
      __hip_atomic_fetch_add(&cbars[l].cnt, 1, __ATOMIC_RELAXED, __HIP_MEMORY_SCOPE_AGENT);
      while (__hip_atomic_load(&cbars[l].cnt, __ATOMIC_RELAXED, __HIP_MEMORY_SCOPE_AGENT) < 16)
        __builtin_amdgcn_s_sleep(1);
      // COH = (all 16 on my physical XCD) AND (probe visibility via L2 path)
      int myx = xcc + 1, coh = 1;
      for (int i = 0; i < 16; ++i)
        coh &= (__hip_atomic_load(&xcctab[l * 16 + i], __ATOMIC_RELAXED, __HIP_MEMORY_SCOPE_AGENT) == myx);
      for (int i = 0; i < 16; ++i) {
        int* qp = &probes[l * 16 + i];
        int pv;
        asm volatile("global_load_dword %0, %1, off sc0" : "=v"(pv) : "v"(qp) : "memory");
        asm volatile("s_waitcnt vmcnt(0)" ::: "memory");
        coh &= (pv == i + 1);
      }
      s_role[2] = coh;
    }
  }
  __syncthreads();

  const int l = s_role[0];
  if (l < 0) return;
  const int rid = s_role[1], coh = s_role[2];
  const int layer = rid >> 3;
  const int u0    = (rid & 7) * 32;

  BarT* bar = bars + l;
  bf16* h0w = h0buf + l * 2 * 32768;  // [2][128][256]
  bf16* h1w = h1buf + l * 2 * 32768;

  const float *W0_, *b0_, *W1_, *b1_; const bf16* xs_; const int* lenp_;
  if (l == 0)      { W0_ = sW0; b0_ = sb0; W1_ = sW1; b1_ = sb1; xs_ = stack_emb; lenp_ = len_s; }
  else if (l == 1) { W0_ = bW0; b0_ = bb0; W1_ = bW1; b1_ = bb1; xs_ = buff_emb;  lenp_ = len_b; }
  else             { W0_ = aW0; b0_ = ab0; W1_ = aW1; b1_ = ab1; xs_ = nullptr;   lenp_ = len_a; }
  const float* W  = layer ? W1_ : W0_;
  const float* bi = layer ? b1_ : b0_;

  switch (l * 4 + layer * 2 + coh) {
    case  0: lstm_role<0, 0, false>(W, bi, xs_, hist_tab, hist_id, lenp_, h0w, h1w, bar, sm, u0); break;
    case  1: lstm_role<0, 0, true >(W, bi, xs_, hist_tab, hist_id, lenp_, h0w, h1w, bar, sm, u0); break;
    case  2: lstm_role<0, 1, false>(W, bi, xs_, hist_tab, hist_id, lenp_, h0w, h1w, bar, sm, u0); break;
    case  3: lstm_role<0, 1, true >(W, bi, xs_, hist_tab, hist_id, lenp_, h0w, h1w, bar, sm, u0); break;
    case  4: lstm_role<1, 0, false>(W, bi, xs_, hist_tab, hist_id, lenp_, h0w, h1w, bar, sm, u0); break;
    case  5: lstm_role<1, 0, true >(W, bi, xs_, hist_tab, hist_id, lenp_, h0w, h1w, bar, sm, u0); break;
    case  6: lstm_role<1, 1, false>(W, bi, xs_, hist_tab, hist_id, lenp_, h0w, h1w, bar, sm, u0); break;
    case  7: lstm_role<1, 1, true >(W, bi, xs_, hist_tab, hist_id, lenp_, h0w, h1w, bar, sm, u0); break;
    case  8: lstm_role<2, 0, false>(W, bi, xs_, hist_tab, hist_id, lenp_, h0w, h1w, bar, sm, u0); break;
    case  9: lstm_role<2, 0, true >(W, bi, xs_, hist_tab, hist_id, lenp_, h0w, h1w, bar, sm, u0); break;
    case 10: lstm_role<2, 1, false>(W, bi, xs_, hist_tab, hist_id, lenp_, h0w, h1w, bar, sm, u0); break;
    case 11: lstm_role<2, 1, true >(W, bi, xs_, hist_tab, hist_id, lenp_, h0w, h1w, bar, sm, u0); break;
  }
}

// =====================================================================
// Kernel 4: out = concat(h_s,h_b,h_a) @ fW + fb
// =====================================================================
__global__ __launch_bounds__(128) void k_final(
    const bf16* h1buf, const float* fW, const float* fb, float* out)
{
  __shared__ float hs[768];
  const int b = blockIdx.x, tid = threadIdx.x;
  for (int i = tid; i < 768; i += 128) {
    int L = i >> 8, u = i & 255;
    hs[i] = (float)h1buf[(L * 2 + 1) * 32768 + b * 256 + u];  // final parity = 1 (T even)
  }
  __syncthreads();
  if (tid < NOUT) {
    float acc = fb[tid];
    for (int u = 0; u < 768; ++u) acc += hs[u] * fW[u * NOUT + tid];
    out[b * NOUT + tid] = acc;
  }
}

// =====================================================================
extern "C" void kernel_launch(void* const* d_in, const int* in_sizes, int n_in,
                              void* d_out, int out_size, void* d_ws, size_t ws_size,
                              hipStream_t stream)
{
  (void)in_sizes; (void)n_in; (void)out_size; (void)ws_size;
  char* ws = (char*)d_ws;
  BarT* bars   = (BarT*)ws;                  // 3*128 = 384 (region 512)
  BarT* cbars  = (BarT*)(ws + 512);          // 3*128 = 384 (region 512)
  int*  taken  = (int*)(ws + 1024);          // 48 ints (1024..1216)
  int*  xcctab = (int*)(ws + 1280);          // 48 ints (1280..1472)
  int*  probes = (int*)(ws + 1536);          // 48 ints (1536..1728, region to 2048)
  bf16* h0buf  = (bf16*)(ws + 2048);         // 3*2*128*256*2 = 393216
  bf16* h1buf  = (bf16*)(ws + 2048 + 393216);                // 393216 -> ends 788480
  bf16* comp_emb  = (bf16*)(ws + 788480);                    // 98304*128*2 = 25165824
  bf16* buff_emb  = (bf16*)(ws + 788480 + 25165824);         // 8192*128*2  = 2097152
  bf16* stack_emb = (bf16*)(ws + 788480 + 25165824 + 2097152); // 6144*128*2 = 1572864

  hipMemsetAsync(ws, 0, 788480, stream);  // control block + h0/h1 init state

  k_emb<<<1664, 256, 0, stream>>>(
      (const int*)d_in[0], (const int*)d_in[1], (const int*)d_in[2], (const int*)d_in[3],
      (const float*)d_in[13], (const float*)d_in[10], (const float*)d_in[14], (const float*)d_in[15],
      comp_emb, buff_emb);

  k_compose<<<384, 256, 0, stream>>>(
      (const int*)d_in[2], (const int*)d_in[4], (const int*)d_in[5],
      comp_emb, (const float*)d_in[11], (const float*)d_in[16], (const float*)d_in[17],
      stack_emb);

  k_lstm<<<256, 512, 0, stream>>>(
      (const float*)d_in[18], (const float*)d_in[19], (const float*)d_in[20], (const float*)d_in[21],
      (const float*)d_in[22], (const float*)d_in[23], (const float*)d_in[24], (const float*)d_in[25],
      (const float*)d_in[26], (const float*)d_in[27], (const float*)d_in[28], (const float*)d_in[29],
      stack_emb, buff_emb, (const float*)d_in[12], (const int*)d_in[6],
      (const int*)d_in[7], (const int*)d_in[8], (const int*)d_in[9],
      h0buf, h1buf, bars, cbars, taken, xcctab, probes);

  k_final<<<128, 128, 0, stream>>>(h1buf, (const float*)d_in[30], (const float*)d_in[31],
                                   (float*)d_out);
}